// Round 3
// baseline (1899.890 us; speedup 1.0000x reference)
//
#include <hip/hip_runtime.h>

// DCCF encoder: U=100000, I=50000, D=64, K=128, L=2, E=1250000, N=150000. f32.
//
// d_out layout (float): [final NxD][gnn LxNxD][intl LxNxD][gaa LxNxD][iaa LxNxD]
//
// R5 = R4 with the nt_store4 compile fix (__builtin_nontemporal_store needs a
// native clang vector type, not HIP_vector_type float4).
//
// R4 changes vs R3:
//  - intent_kernel: __launch_bounds__(64, 2). R3 omitted the min-waves arg;
//    backend could cap at 128 VGPRs and spill a[128] to scratch (theory for
//    the +310us gap vs prediction). (64,2) -> explicit 256-VGPR cap, no spill,
//    2 waves/SIMD (8 blocks/CU x 16.6KB LDS = 133KB < 160KB).
//  - scan: single-block kernel (whole GPU idle on 1 CU) replaced by 3-kernel
//    parallel scan: scanA per-chunk sums (256 blocks), scanB scan of 256
//    partials (1 tiny block), scanC re-scan chunks + write row_ptr/cursor.
//  - fin = ek0+ek1+ek2 restructure: init no longer writes fin; passB layer 0
//    skips fin entirely; last-layer passB skips ek_next store and writes
//    fin = ek0 + ek1 + en directly (reads ek0 from ekA). ~153MB less traffic.
//  - gaa/iaa/fin stores are non-temporal (never re-read) to keep ek/gnn/intl
//    hotter in L2 for passB's gathers.

#define U_CNT 100000
#define I_CNT 50000
#define D_DIM 64
#define K_DIM 128
#define L_LAYERS 2
#define E_CNT 1250000
#define N_CNT (U_CNT + I_CNT)
#define EPSF 1e-12f

#define UBLK ((U_CNT + 63) / 64)  // 1563 (last block: 32 users)
#define IBLK ((I_CNT + 63) / 64)  // 782  (last block: 16 items)

#define SC_BLOCKS 256
#define SC_TPB 256
#define SC_CHUNK ((N_CNT + SC_BLOCKS - 1) / SC_BLOCKS)  // 586

typedef float vfloat4 __attribute__((ext_vector_type(4)));

__device__ __forceinline__ void nt_store4(float* p, float4 v) {
  vfloat4 nv;
  nv.x = v.x;
  nv.y = v.y;
  nv.z = v.z;
  nv.w = v.w;
  __builtin_nontemporal_store(nv, (vfloat4*)p);
}

__global__ void init_kernel(const float* __restrict__ ue, const float* __restrict__ ie,
                            float* __restrict__ ek) {
  int idx = blockIdx.x * blockDim.x + threadIdx.x;
  const int total = N_CNT * D_DIM;
  for (; idx < total; idx += gridDim.x * blockDim.x) {
    float v = (idx < U_CNT * D_DIM) ? ue[idx] : ie[idx - U_CNT * D_DIM];
    ek[idx] = v;
  }
}

__global__ void hist_kernel(const int* __restrict__ h_idx, int* __restrict__ counts) {
  int e = blockIdx.x * blockDim.x + threadIdx.x;
  for (; e < E_CNT; e += gridDim.x * blockDim.x) atomicAdd(&counts[h_idx[e]], 1);
}

// --- parallel scan: A (per-chunk sums), B (scan 256 partials), C (re-scan) ---
__global__ void scanA_kernel(const int* __restrict__ counts, int* __restrict__ partial) {
  int b = blockIdx.x, tid = threadIdx.x, lane = tid & 63, wv = tid >> 6;
  int lo = b * SC_CHUNK;
  int hi = lo + SC_CHUNK;
  if (hi > N_CNT) hi = N_CNT;
  int s = 0;
  for (int i = lo + tid; i < hi; i += SC_TPB) s += counts[i];
#pragma unroll
  for (int off = 32; off > 0; off >>= 1) s += __shfl_xor(s, off, 64);
  __shared__ int ws[4];
  if (lane == 0) ws[wv] = s;
  __syncthreads();
  if (tid == 0) partial[b] = ws[0] + ws[1] + ws[2] + ws[3];
}

__global__ void scanB_kernel(const int* __restrict__ partial, int* __restrict__ offs) {
  int tid = threadIdx.x, lane = tid & 63, wv = tid >> 6;
  int v = partial[tid];
  int x = v;
#pragma unroll
  for (int off = 1; off < 64; off <<= 1) {
    int y = __shfl_up(x, off, 64);
    if (lane >= off) x += y;
  }
  __shared__ int wt[4];
  if (lane == 63) wt[wv] = x;
  __syncthreads();
  int add = 0;
  for (int w = 0; w < wv; w++) add += wt[w];
  offs[tid] = add + x - v;  // exclusive
}

__global__ void scanC_kernel(const int* __restrict__ counts, const int* __restrict__ offs,
                             int* __restrict__ row_ptr, int* __restrict__ cursor) {
  int b = blockIdx.x, tid = threadIdx.x, lane = tid & 63, wv = tid >> 6;
  __shared__ int wt[4];
  int lo = b * SC_CHUNK;
  int hi = lo + SC_CHUNK;
  if (hi > N_CNT) hi = N_CNT;
  int carry = offs[b];
  for (int base = lo; base < hi; base += SC_TPB) {
    int i = base + tid;
    int v = (i < hi) ? counts[i] : 0;
    int x = v;
#pragma unroll
    for (int off = 1; off < 64; off <<= 1) {
      int y = __shfl_up(x, off, 64);
      if (lane >= off) x += y;
    }
    if (lane == 63) wt[wv] = x;
    __syncthreads();
    int add = carry;
    for (int w = 0; w < wv; w++) add += wt[w];
    if (i < hi) {
      int e = add + x - v;
      row_ptr[i] = e;
      cursor[i] = e;
    }
    int tot = wt[0] + wt[1] + wt[2] + wt[3];
    __syncthreads();
    carry += tot;
  }
  if (b == 0 && tid == 0) row_ptr[N_CNT] = E_CNT;
}

__global__ void scatter_kernel(const int* __restrict__ h_idx, const int* __restrict__ t_idx,
                               const float* __restrict__ adj_vals, int* __restrict__ cursor,
                               int* __restrict__ t_sorted, float* __restrict__ v_sorted) {
  int e = blockIdx.x * blockDim.x + threadIdx.x;
  for (; e < E_CNT; e += gridDim.x * blockDim.x) {
    int h = h_idx[e];
    int pos = atomicAdd(&cursor[h], 1);
    t_sorted[pos] = t_idx[e];
    v_sorted[pos] = adj_vals[e];
  }
}

// One-shot: W [64][128] -> WT [128][64] for both intent matrices.
__global__ void transposeW_kernel(const float* __restrict__ Wu, const float* __restrict__ Wi,
                                  float* __restrict__ WuT, float* __restrict__ WiT) {
  int idx = blockIdx.x * blockDim.x + threadIdx.x;
  for (; idx < 2 * D_DIM * K_DIM; idx += gridDim.x * blockDim.x) {
    int w = idx >> 13, r = idx & (D_DIM * K_DIM - 1);
    int d = r >> 7, k = r & (K_DIM - 1);
    const float* W = w ? Wi : Wu;
    float* WT = w ? WiT : WuT;
    WT[k * D_DIM + d] = W[d * K_DIM + k];
  }
}

// gnn = spmm(adj_vals, ek), 4 edges/iter, float4 lanes; also 1/||gnn row||
__global__ void spmm_gnn_kernel(const float* __restrict__ ek, const int* __restrict__ t_sorted,
                                const float* __restrict__ v_sorted,
                                const int* __restrict__ row_ptr, float* __restrict__ gnn,
                                float* __restrict__ invn_g) {
  int wv = threadIdx.x >> 6, lane = threadIdx.x & 63;
  int slot = lane >> 4, f = (lane & 15) << 2;
  int n = blockIdx.x * 4 + wv;
  if (n >= N_CNT) return;
  int start = row_ptr[n], end = row_ptr[n + 1];
  float ax = 0.f, ay = 0.f, az = 0.f, aw = 0.f;
  for (int i = start; i < end; i += 4) {
    int idx = i + slot;
    int ic = (idx < end) ? idx : (end - 1);
    int t = t_sorted[ic];
    float v = v_sorted[ic];
    if (idx >= end) v = 0.f;
    const float4 x = *(const float4*)(ek + (size_t)t * D_DIM + f);
    ax = fmaf(v, x.x, ax);
    ay = fmaf(v, x.y, ay);
    az = fmaf(v, x.z, az);
    aw = fmaf(v, x.w, aw);
  }
#pragma unroll
  for (int off = 16; off <= 32; off <<= 1) {
    ax += __shfl_xor(ax, off, 64);
    ay += __shfl_xor(ay, off, 64);
    az += __shfl_xor(az, off, 64);
    aw += __shfl_xor(aw, off, 64);
  }
  if (slot == 0) {
    float4 o = make_float4(ax, ay, az, aw);
    *(float4*)(gnn + (size_t)n * D_DIM + f) = o;
  }
  float ss = ax * ax + ay * ay + az * az + aw * aw;
#pragma unroll
  for (int off = 1; off <= 8; off <<= 1) ss += __shfl_xor(ss, off, 64);
  if (lane == 0) invn_g[n] = 1.f / fmaxf(sqrtf(ss), EPSF);
}

// intl = softmax(ek @ W) @ W^T. lane = node, 64 nodes per wave, 1 wave/block.
// a[k] and o[d] lane-local; softmax lane-local; W via wave-uniform scalar loads.
// __launch_bounds__(64, 2): 2 waves/EU -> 256-VGPR cap, no spill of a[128]+o[64].
__global__ __launch_bounds__(64, 2) void intent_kernel(
    const float* __restrict__ ek, const float* __restrict__ Wu, const float* __restrict__ WuT,
    const float* __restrict__ Wi, const float* __restrict__ WiT, float* __restrict__ intl,
    float* __restrict__ invn_i) {
  __shared__ float T[D_DIM * 65];  // padded: bank = (word + row-ish) -> 2-way max
  const int lane = threadIdx.x;
  const int b = blockIdx.x;
  int n0, cnt;
  const float *W, *WT;
  if (b < UBLK) {
    n0 = b * 64;
    cnt = (U_CNT - n0 < 64) ? (U_CNT - n0) : 64;
    W = Wu;
    WT = WuT;
  } else {
    n0 = U_CNT + (b - UBLK) * 64;
    cnt = (N_CNT - n0 < 64) ? (N_CNT - n0) : 64;
    W = Wi;
    WT = WiT;
  }
  const int h = lane >> 4, m = lane & 15;

  // Phase 0: coalesced float4 loads of 64 node rows -> transposed into LDS.
#pragma unroll
  for (int i = 0; i < 16; i++) {
    int r = i * 4 + h;  // node row within tile
    float4 v = make_float4(0.f, 0.f, 0.f, 0.f);
    if (r < cnt) v = *(const float4*)(ek + (size_t)(n0 + r) * D_DIM + m * 4);
    T[(4 * m + 0) * 65 + r] = v.x;
    T[(4 * m + 1) * 65 + r] = v.y;
    T[(4 * m + 2) * 65 + r] = v.z;
    T[(4 * m + 3) * 65 + r] = v.w;
  }
  __syncthreads();

  // Phase 1: a[k] = sum_d e[d] * W[d][k]. W row is wave-uniform -> s_load.
  float a[K_DIM];
#pragma unroll
  for (int k = 0; k < K_DIM; k++) a[k] = 0.f;
#pragma unroll 2
  for (int d = 0; d < D_DIM; d++) {
    float ed = T[d * 65 + lane];  // bank (d+lane)%32 -> 2-way, free
    const float* __restrict__ wr = W + d * K_DIM;
#pragma unroll
    for (int k = 0; k < K_DIM; k++) a[k] = fmaf(wr[k], ed, a[k]);
  }

  // Lane-local softmax over a[0..127] (4 chains to break dep latency).
  float m0 = a[0], m1 = a[1], m2 = a[2], m3 = a[3];
#pragma unroll
  for (int k = 4; k < K_DIM; k += 4) {
    m0 = fmaxf(m0, a[k]);
    m1 = fmaxf(m1, a[k + 1]);
    m2 = fmaxf(m2, a[k + 2]);
    m3 = fmaxf(m3, a[k + 3]);
  }
  float mx = fmaxf(fmaxf(m0, m1), fmaxf(m2, m3));
  float s0 = 0.f, s1 = 0.f, s2 = 0.f, s3 = 0.f;
#pragma unroll
  for (int k = 0; k < K_DIM; k += 4) {
    a[k] = __expf(a[k] - mx);
    s0 += a[k];
    a[k + 1] = __expf(a[k + 1] - mx);
    s1 += a[k + 1];
    a[k + 2] = __expf(a[k + 2] - mx);
    s2 += a[k + 2];
    a[k + 3] = __expf(a[k + 3] - mx);
    s3 += a[k + 3];
  }
  float inv_s = 1.f / ((s0 + s1) + (s2 + s3));  // normalize folded into epilogue

  // Phase 2: o[d] = sum_k p[k] * WT[k][d], k rolled. p streamed via LDS in two
  // 64-row halves so the rolled k never runtime-indexes a register array.
  float o[D_DIM];
#pragma unroll
  for (int d = 0; d < D_DIM; d++) o[d] = 0.f;

  __syncthreads();
#pragma unroll
  for (int k = 0; k < 64; k++) T[k * 65 + lane] = a[k];
  __syncthreads();
#pragma unroll 2
  for (int k = 0; k < 64; k++) {
    float pk = T[k * 65 + lane];
    const float* __restrict__ wr = WT + k * D_DIM;
#pragma unroll
    for (int d = 0; d < D_DIM; d++) o[d] = fmaf(wr[d], pk, o[d]);
  }
  __syncthreads();
#pragma unroll
  for (int k = 0; k < 64; k++) T[k * 65 + lane] = a[k + 64];
  __syncthreads();
#pragma unroll 2
  for (int k = 0; k < 64; k++) {
    float pk = T[k * 65 + lane];
    const float* __restrict__ wr = WT + (k + 64) * D_DIM;
#pragma unroll
    for (int d = 0; d < D_DIM; d++) o[d] = fmaf(wr[d], pk, o[d]);
  }

  // Epilogue: normalize, row inv-norm, transpose back through LDS, coalesced store.
  float ns = 0.f;
#pragma unroll
  for (int d = 0; d < D_DIM; d++) {
    o[d] *= inv_s;
    ns = fmaf(o[d], o[d], ns);
  }
  if (lane < cnt) invn_i[n0 + lane] = 1.f / fmaxf(sqrtf(ns), EPSF);

  __syncthreads();
#pragma unroll
  for (int d = 0; d < D_DIM; d++) T[d * 65 + lane] = o[d];
  __syncthreads();
#pragma unroll
  for (int i = 0; i < 16; i++) {
    int r = i * 4 + h;
    if (r < cnt) {
      float4 v = make_float4(T[(4 * m + 0) * 65 + r], T[(4 * m + 1) * 65 + r],
                             T[(4 * m + 2) * 65 + r], T[(4 * m + 3) * 65 + r]);
      *(float4*)(intl + (size_t)(n0 + r) * D_DIM + m * 4) = v;
    }
  }
}

// Fused adaptive pass: 4 edges/iter, float4 lanes. Computes both alphas, row
// sums, alpha-weighted ek accum (d_inv factored out), gaa/iaa, and either
// ek_next (LAST=false) or fin = ek0 + ek1 + ek2 (LAST=true).
template <bool LAST>
__global__ void passB_kernel(const float* __restrict__ ek, const float* __restrict__ gnn,
                             const float* __restrict__ intl, const float* __restrict__ invn_g,
                             const float* __restrict__ invn_i, const int* __restrict__ t_sorted,
                             const int* __restrict__ row_ptr, float* __restrict__ gaa,
                             float* __restrict__ iaa, float* __restrict__ ek_next,
                             const float* __restrict__ ek0, float* __restrict__ fin) {
  int wv = threadIdx.x >> 6, lane = threadIdx.x & 63;
  int slot = lane >> 4, f = (lane & 15) << 2;
  int n = blockIdx.x * 4 + wv;
  if (n >= N_CNT) return;
  int start = row_ptr[n], end = row_ptr[n + 1];
  const float4 gh = *(const float4*)(gnn + (size_t)n * D_DIM + f);
  const float4 ih = *(const float4*)(intl + (size_t)n * D_DIM + f);
  float ig = invn_g[n], ii = invn_i[n];
  float rs_g = 0.f, rs_i = 0.f;
  float gx = 0.f, gy = 0.f, gz = 0.f, gw = 0.f;
  float ix = 0.f, iy = 0.f, iz = 0.f, iw = 0.f;
  for (int i = start; i < end; i += 4) {
    int idx = i + slot;
    int ic = (idx < end) ? idx : (end - 1);
    int t = t_sorted[ic];
    size_t rb = (size_t)t * D_DIM + f;
    const float4 gt = *(const float4*)(gnn + rb);
    const float4 it = *(const float4*)(intl + rb);
    const float4 et = *(const float4*)(ek + rb);
    float ivg = invn_g[t];
    float ivi = invn_i[t];
    float dg = gh.x * gt.x + gh.y * gt.y + gh.z * gt.z + gh.w * gt.w;
    float di = ih.x * it.x + ih.y * it.y + ih.z * it.z + ih.w * it.w;
#pragma unroll
    for (int off = 1; off <= 8; off <<= 1) {
      dg += __shfl_xor(dg, off, 64);
      di += __shfl_xor(di, off, 64);
    }
    float ag = fmaf(dg * ig, ivg, 1.f) * 0.5f;
    float ai = fmaf(di * ii, ivi, 1.f) * 0.5f;
    if (idx >= end) { ag = 0.f; ai = 0.f; }
    rs_g += ag;
    rs_i += ai;
    gx = fmaf(ag, et.x, gx);
    gy = fmaf(ag, et.y, gy);
    gz = fmaf(ag, et.z, gz);
    gw = fmaf(ag, et.w, gw);
    ix = fmaf(ai, et.x, ix);
    iy = fmaf(ai, et.y, iy);
    iz = fmaf(ai, et.z, iz);
    iw = fmaf(ai, et.w, iw);
  }
#pragma unroll
  for (int off = 16; off <= 32; off <<= 1) {
    rs_g += __shfl_xor(rs_g, off, 64);
    rs_i += __shfl_xor(rs_i, off, 64);
    gx += __shfl_xor(gx, off, 64);
    gy += __shfl_xor(gy, off, 64);
    gz += __shfl_xor(gz, off, 64);
    gw += __shfl_xor(gw, off, 64);
    ix += __shfl_xor(ix, off, 64);
    iy += __shfl_xor(iy, off, 64);
    iz += __shfl_xor(iz, off, 64);
    iw += __shfl_xor(iw, off, 64);
  }
  float dgi = (rs_g > 0.f) ? 1.f / rs_g : 0.f;
  float dii = (rs_i > 0.f) ? 1.f / rs_i : 0.f;
  if (slot == 0) {
    size_t ob = (size_t)n * D_DIM + f;
    float4 ga = make_float4(gx * dgi, gy * dgi, gz * dgi, gw * dgi);
    float4 ia = make_float4(ix * dii, iy * dii, iz * dii, iw * dii);
    nt_store4(gaa + ob, ga);
    nt_store4(iaa + ob, ia);
    const float4 eh = *(const float4*)(ek + ob);
    float4 en = make_float4(gh.x + ih.x + ga.x + ia.x + eh.x, gh.y + ih.y + ga.y + ia.y + eh.y,
                            gh.z + ih.z + ga.z + ia.z + eh.z, gh.w + ih.w + ga.w + ia.w + eh.w);
    if (LAST) {
      // fin = ek0 + ek1 + ek2 = ek0 + eh + en
      const float4 e0 = *(const float4*)(ek0 + ob);
      float4 fo = make_float4(e0.x + eh.x + en.x, e0.y + eh.y + en.y, e0.z + eh.z + en.z,
                              e0.w + eh.w + en.w);
      nt_store4(fin + ob, fo);
    } else {
      *(float4*)(ek_next + ob) = en;
    }
  }
}

extern "C" void kernel_launch(void* const* d_in, const int* in_sizes, int n_in, void* d_out,
                              int out_size, void* d_ws, size_t ws_size, hipStream_t stream) {
  const float* user_emb = (const float*)d_in[0];
  const float* item_emb = (const float*)d_in[1];
  const float* user_intent = (const float*)d_in[2];
  const float* item_intent = (const float*)d_in[3];
  const float* adj_vals = (const float*)d_in[4];
  const int* h_idx = (const int*)d_in[5];
  const int* t_idx = (const int*)d_in[6];

  float* out = (float*)d_out;
  float* fin = out;
  float* gnn_base = out + (size_t)N_CNT * D_DIM;
  float* intl_base = gnn_base + (size_t)L_LAYERS * N_CNT * D_DIM;
  float* gaa_base = intl_base + (size_t)L_LAYERS * N_CNT * D_DIM;
  float* iaa_base = gaa_base + (size_t)L_LAYERS * N_CNT * D_DIM;

  float* ws = (float*)d_ws;
  float* ekA = ws;                                // N*D (ek0 — preserved)
  float* ekB = ekA + (size_t)N_CNT * D_DIM;       // N*D (ek1)
  float* ekC = ekB + (size_t)N_CNT * D_DIM;       // N*D (spare / ek2 if L>2)
  float* v_sorted = ekC + (size_t)N_CNT * D_DIM;  // E
  float* invn_g = v_sorted + E_CNT;               // N
  float* invn_i = invn_g + N_CNT;                 // N
  int* t_sorted = (int*)(invn_i + N_CNT);         // E
  int* row_ptr = t_sorted + E_CNT;                // N+1
  int* counts = row_ptr + (N_CNT + 1);            // N
  int* cursor = counts + N_CNT;                   // N
  int* partial = cursor + N_CNT;                  // SC_BLOCKS
  int* offs = partial + SC_BLOCKS;                // SC_BLOCKS
  float* wtu = (float*)(offs + SC_BLOCKS);        // D*K  (W_u^T)
  float* wti = wtu + (size_t)D_DIM * K_DIM;       // D*K  (W_i^T)

  (void)hipMemsetAsync(counts, 0, N_CNT * sizeof(int), stream);
  init_kernel<<<2048, 256, 0, stream>>>(user_emb, item_emb, ekA);
  hist_kernel<<<2048, 256, 0, stream>>>(h_idx, counts);
  transposeW_kernel<<<32, 512, 0, stream>>>(user_intent, item_intent, wtu, wti);
  scanA_kernel<<<SC_BLOCKS, SC_TPB, 0, stream>>>(counts, partial);
  scanB_kernel<<<1, SC_BLOCKS, 0, stream>>>(partial, offs);
  scanC_kernel<<<SC_BLOCKS, SC_TPB, 0, stream>>>(counts, offs, row_ptr, cursor);
  scatter_kernel<<<2048, 256, 0, stream>>>(h_idx, t_idx, adj_vals, cursor, t_sorted, v_sorted);

  const int nodeBlocks = (N_CNT + 3) / 4;
  const int intentBlocks = UBLK + IBLK;

  // Layer 0: ekA (ek0) -> ekB (ek1). Layer 1 (last): fin = ekA + ekB + en.
  float* ek = ekA;
  float* ekn = ekB;
  for (int l = 0; l < L_LAYERS; l++) {
    float* gnn = gnn_base + (size_t)l * N_CNT * D_DIM;
    float* intl = intl_base + (size_t)l * N_CNT * D_DIM;
    float* gaa = gaa_base + (size_t)l * N_CNT * D_DIM;
    float* iaa = iaa_base + (size_t)l * N_CNT * D_DIM;
    spmm_gnn_kernel<<<nodeBlocks, 256, 0, stream>>>(ek, t_sorted, v_sorted, row_ptr, gnn, invn_g);
    intent_kernel<<<intentBlocks, 64, 0, stream>>>(ek, user_intent, wtu, item_intent, wti, intl,
                                                   invn_i);
    if (l == L_LAYERS - 1) {
      passB_kernel<true><<<nodeBlocks, 256, 0, stream>>>(ek, gnn, intl, invn_g, invn_i, t_sorted,
                                                         row_ptr, gaa, iaa, nullptr, ekA, fin);
    } else {
      passB_kernel<false><<<nodeBlocks, 256, 0, stream>>>(ek, gnn, intl, invn_g, invn_i, t_sorted,
                                                          row_ptr, gaa, iaa, ekn, nullptr, nullptr);
      float* tmp = ek;
      ek = ekn;
      ekn = (l == 0) ? ekC : tmp;  // never clobber ekA (ek0, needed by last layer)
    }
  }
}

// Round 4
// 1145.354 us; speedup vs baseline: 1.6588x; 1.6588x over previous
//
#include <hip/hip_runtime.h>

// DCCF encoder: U=100000, I=50000, D=64, K=128, L=2, E=1250000, N=150000. f32.
//
// d_out layout (float): [final NxD][gnn LxNxD][intl LxNxD][gaa LxNxD][iaa LxNxD]
//
// R6 changes vs R5:
//  - intent_kernel rewritten as a register-tiled vector GEMM (256 thr, 16x16
//    thread grid, thread owns 4 nodes x 8 k / 4 nodes x 4 d). R5's
//    "wave-uniform W -> s_load" design was scalar-pipe latency-bound
//    (VALUBusy 7.8%, SGPR 112: a 512B W row can't live in SGPRs, so the
//    compiler serialized s_load/lgkmcnt chunks). Now W/WT are read with
//    per-lane vector loads (L2-resident, manually double-buffered), E and P
//    go through one reused LDS tile [128][65] with conflict-free reads, and
//    softmax reduces over the 16-lane tx group via shfl_xor.
//  - per-thread arrays <=32 floats, statically indexed -> no scratch.

#define U_CNT 100000
#define I_CNT 50000
#define D_DIM 64
#define K_DIM 128
#define L_LAYERS 2
#define E_CNT 1250000
#define N_CNT (U_CNT + I_CNT)
#define EPSF 1e-12f

#define UBLK ((U_CNT + 63) / 64)  // 1563 (last block: 32 users)
#define IBLK ((I_CNT + 63) / 64)  // 782  (last block: 16 items)

#define SC_BLOCKS 256
#define SC_TPB 256
#define SC_CHUNK ((N_CNT + SC_BLOCKS - 1) / SC_BLOCKS)  // 586

typedef float vfloat4 __attribute__((ext_vector_type(4)));

__device__ __forceinline__ void nt_store4(float* p, float4 v) {
  vfloat4 nv;
  nv.x = v.x;
  nv.y = v.y;
  nv.z = v.z;
  nv.w = v.w;
  __builtin_nontemporal_store(nv, (vfloat4*)p);
}

__global__ void init_kernel(const float* __restrict__ ue, const float* __restrict__ ie,
                            float* __restrict__ ek) {
  int idx = blockIdx.x * blockDim.x + threadIdx.x;
  const int total = N_CNT * D_DIM;
  for (; idx < total; idx += gridDim.x * blockDim.x) {
    float v = (idx < U_CNT * D_DIM) ? ue[idx] : ie[idx - U_CNT * D_DIM];
    ek[idx] = v;
  }
}

__global__ void hist_kernel(const int* __restrict__ h_idx, int* __restrict__ counts) {
  int e = blockIdx.x * blockDim.x + threadIdx.x;
  for (; e < E_CNT; e += gridDim.x * blockDim.x) atomicAdd(&counts[h_idx[e]], 1);
}

// --- parallel scan: A (per-chunk sums), B (scan 256 partials), C (re-scan) ---
__global__ void scanA_kernel(const int* __restrict__ counts, int* __restrict__ partial) {
  int b = blockIdx.x, tid = threadIdx.x, lane = tid & 63, wv = tid >> 6;
  int lo = b * SC_CHUNK;
  int hi = lo + SC_CHUNK;
  if (hi > N_CNT) hi = N_CNT;
  int s = 0;
  for (int i = lo + tid; i < hi; i += SC_TPB) s += counts[i];
#pragma unroll
  for (int off = 32; off > 0; off >>= 1) s += __shfl_xor(s, off, 64);
  __shared__ int ws[4];
  if (lane == 0) ws[wv] = s;
  __syncthreads();
  if (tid == 0) partial[b] = ws[0] + ws[1] + ws[2] + ws[3];
}

__global__ void scanB_kernel(const int* __restrict__ partial, int* __restrict__ offs) {
  int tid = threadIdx.x, lane = tid & 63, wv = tid >> 6;
  int v = partial[tid];
  int x = v;
#pragma unroll
  for (int off = 1; off < 64; off <<= 1) {
    int y = __shfl_up(x, off, 64);
    if (lane >= off) x += y;
  }
  __shared__ int wt[4];
  if (lane == 63) wt[wv] = x;
  __syncthreads();
  int add = 0;
  for (int w = 0; w < wv; w++) add += wt[w];
  offs[tid] = add + x - v;  // exclusive
}

__global__ void scanC_kernel(const int* __restrict__ counts, const int* __restrict__ offs,
                             int* __restrict__ row_ptr, int* __restrict__ cursor) {
  int b = blockIdx.x, tid = threadIdx.x, lane = tid & 63, wv = tid >> 6;
  __shared__ int wt[4];
  int lo = b * SC_CHUNK;
  int hi = lo + SC_CHUNK;
  if (hi > N_CNT) hi = N_CNT;
  int carry = offs[b];
  for (int base = lo; base < hi; base += SC_TPB) {
    int i = base + tid;
    int v = (i < hi) ? counts[i] : 0;
    int x = v;
#pragma unroll
    for (int off = 1; off < 64; off <<= 1) {
      int y = __shfl_up(x, off, 64);
      if (lane >= off) x += y;
    }
    if (lane == 63) wt[wv] = x;
    __syncthreads();
    int add = carry;
    for (int w = 0; w < wv; w++) add += wt[w];
    if (i < hi) {
      int e = add + x - v;
      row_ptr[i] = e;
      cursor[i] = e;
    }
    int tot = wt[0] + wt[1] + wt[2] + wt[3];
    __syncthreads();
    carry += tot;
  }
  if (b == 0 && tid == 0) row_ptr[N_CNT] = E_CNT;
}

__global__ void scatter_kernel(const int* __restrict__ h_idx, const int* __restrict__ t_idx,
                               const float* __restrict__ adj_vals, int* __restrict__ cursor,
                               int* __restrict__ t_sorted, float* __restrict__ v_sorted) {
  int e = blockIdx.x * blockDim.x + threadIdx.x;
  for (; e < E_CNT; e += gridDim.x * blockDim.x) {
    int h = h_idx[e];
    int pos = atomicAdd(&cursor[h], 1);
    t_sorted[pos] = t_idx[e];
    v_sorted[pos] = adj_vals[e];
  }
}

// One-shot: W [64][128] -> WT [128][64] for both intent matrices.
__global__ void transposeW_kernel(const float* __restrict__ Wu, const float* __restrict__ Wi,
                                  float* __restrict__ WuT, float* __restrict__ WiT) {
  int idx = blockIdx.x * blockDim.x + threadIdx.x;
  for (; idx < 2 * D_DIM * K_DIM; idx += gridDim.x * blockDim.x) {
    int w = idx >> 13, r = idx & (D_DIM * K_DIM - 1);
    int d = r >> 7, k = r & (K_DIM - 1);
    const float* W = w ? Wi : Wu;
    float* WT = w ? WiT : WuT;
    WT[k * D_DIM + d] = W[d * K_DIM + k];
  }
}

// gnn = spmm(adj_vals, ek), 4 edges/iter, float4 lanes; also 1/||gnn row||
__global__ void spmm_gnn_kernel(const float* __restrict__ ek, const int* __restrict__ t_sorted,
                                const float* __restrict__ v_sorted,
                                const int* __restrict__ row_ptr, float* __restrict__ gnn,
                                float* __restrict__ invn_g) {
  int wv = threadIdx.x >> 6, lane = threadIdx.x & 63;
  int slot = lane >> 4, f = (lane & 15) << 2;
  int n = blockIdx.x * 4 + wv;
  if (n >= N_CNT) return;
  int start = row_ptr[n], end = row_ptr[n + 1];
  float ax = 0.f, ay = 0.f, az = 0.f, aw = 0.f;
  for (int i = start; i < end; i += 4) {
    int idx = i + slot;
    int ic = (idx < end) ? idx : (end - 1);
    int t = t_sorted[ic];
    float v = v_sorted[ic];
    if (idx >= end) v = 0.f;
    const float4 x = *(const float4*)(ek + (size_t)t * D_DIM + f);
    ax = fmaf(v, x.x, ax);
    ay = fmaf(v, x.y, ay);
    az = fmaf(v, x.z, az);
    aw = fmaf(v, x.w, aw);
  }
#pragma unroll
  for (int off = 16; off <= 32; off <<= 1) {
    ax += __shfl_xor(ax, off, 64);
    ay += __shfl_xor(ay, off, 64);
    az += __shfl_xor(az, off, 64);
    aw += __shfl_xor(aw, off, 64);
  }
  if (slot == 0) {
    float4 o = make_float4(ax, ay, az, aw);
    *(float4*)(gnn + (size_t)n * D_DIM + f) = o;
  }
  float ss = ax * ax + ay * ay + az * az + aw * aw;
#pragma unroll
  for (int off = 1; off <= 8; off <<= 1) ss += __shfl_xor(ss, off, 64);
  if (lane == 0) invn_g[n] = 1.f / fmaxf(sqrtf(ss), EPSF);
}

// intl = softmax(ek @ W) @ W^T for a 64-node tile. 256 threads, 16x16 grid:
// tx = tid&15 owns 8 k-cols (phase 1) / 4 d-cols (phase 2); ty = tid>>4 owns
// 4 node-rows. E and P share one LDS tile buf[128][65] (E rows 0..63 are dead
// before P is written). W/WT operands are per-lane vector global loads
// (L2-resident; tx-dependent address so the compiler cannot scalarize them),
// manually double-buffered across the inner loop.
__global__ __launch_bounds__(256, 4) void intent_kernel(
    const float* __restrict__ ek, const float* __restrict__ Wu, const float* __restrict__ WuT,
    const float* __restrict__ Wi, const float* __restrict__ WiT, float* __restrict__ intl,
    float* __restrict__ invn_i) {
  __shared__ float buf[K_DIM * 65];
  const int tid = threadIdx.x;
  const int tx = tid & 15, ty = tid >> 4;
  const int b = blockIdx.x;
  int n0, cnt;
  const float *W, *WT;
  if (b < UBLK) {
    n0 = b * 64;
    cnt = (U_CNT - n0 < 64) ? (U_CNT - n0) : 64;
    W = Wu;
    WT = WuT;
  } else {
    n0 = U_CNT + (b - UBLK) * 64;
    cnt = (N_CNT - n0 < 64) ? (N_CNT - n0) : 64;
    W = Wi;
    WT = WiT;
  }

  // Stage E: buf[node][d], pad 65. Coalesced float4 reads; scalar LDS writes
  // (bank = (r + 4q + j) % 32 -> 2-way max = free). Zero-fill rows >= cnt.
#pragma unroll
  for (int it = 0; it < 4; it++) {
    int idx = tid + 256 * it;
    int r = idx >> 4, q = idx & 15;
    float4 v = make_float4(0.f, 0.f, 0.f, 0.f);
    if (r < cnt) v = *(const float4*)(ek + (size_t)(n0 + r) * D_DIM + q * 4);
    buf[r * 65 + 4 * q + 0] = v.x;
    buf[r * 65 + 4 * q + 1] = v.y;
    buf[r * 65 + 4 * q + 2] = v.z;
    buf[r * 65 + 4 * q + 3] = v.w;
  }
  __syncthreads();

  // Phase 1: a[i][j] = sum_d E[4ty+i][d] * W[d][8tx+j]. 32 FMA / 4 LDS b32 / d.
  float a[4][8];
#pragma unroll
  for (int i = 0; i < 4; i++)
#pragma unroll
    for (int j = 0; j < 8; j++) a[i][j] = 0.f;

  const float* wp = W + 8 * tx;
  float4 w0 = *(const float4*)(wp);
  float4 w1 = *(const float4*)(wp + 4);
  for (int d = 0; d < D_DIM; d++) {
    float4 nw0, nw1;
    if (d < D_DIM - 1) {
      nw0 = *(const float4*)(wp + (d + 1) * K_DIM);
      nw1 = *(const float4*)(wp + (d + 1) * K_DIM + 4);
    }
    float e0 = buf[(4 * ty + 0) * 65 + d];
    float e1 = buf[(4 * ty + 1) * 65 + d];
    float e2 = buf[(4 * ty + 2) * 65 + d];
    float e3 = buf[(4 * ty + 3) * 65 + d];
    float wv[8] = {w0.x, w0.y, w0.z, w0.w, w1.x, w1.y, w1.z, w1.w};
    float ev[4] = {e0, e1, e2, e3};
#pragma unroll
    for (int i = 0; i < 4; i++)
#pragma unroll
      for (int j = 0; j < 8; j++) a[i][j] = fmaf(ev[i], wv[j], a[i][j]);
    w0 = nw0;
    w1 = nw1;
  }

  // Softmax over k (distributed: 8 local + 16-lane tx-group shfl reduce).
  float mx[4], sm[4], inv_s[4];
#pragma unroll
  for (int i = 0; i < 4; i++) {
    float m = a[i][0];
#pragma unroll
    for (int j = 1; j < 8; j++) m = fmaxf(m, a[i][j]);
    mx[i] = m;
  }
#pragma unroll
  for (int off = 1; off <= 8; off <<= 1)
#pragma unroll
    for (int i = 0; i < 4; i++) mx[i] = fmaxf(mx[i], __shfl_xor(mx[i], off, 64));
#pragma unroll
  for (int i = 0; i < 4; i++) {
    float s = 0.f;
#pragma unroll
    for (int j = 0; j < 8; j++) {
      a[i][j] = __expf(a[i][j] - mx[i]);
      s += a[i][j];
    }
    sm[i] = s;
  }
#pragma unroll
  for (int off = 1; off <= 8; off <<= 1)
#pragma unroll
    for (int i = 0; i < 4; i++) sm[i] += __shfl_xor(sm[i], off, 64);
#pragma unroll
  for (int i = 0; i < 4; i++) inv_s[i] = 1.f / sm[i];

  // P -> LDS: buf[k][node] (overwrites E; all E reads completed above).
  __syncthreads();
#pragma unroll
  for (int i = 0; i < 4; i++)
#pragma unroll
    for (int j = 0; j < 8; j++) buf[(8 * tx + j) * 65 + 4 * ty + i] = a[i][j];
  __syncthreads();

  // Phase 2: o[i][j] = sum_k P[4ty+i][k] * WT[k][4tx+j]. 16 FMA / 4 LDS b32 / k.
  float o[4][4];
#pragma unroll
  for (int i = 0; i < 4; i++)
#pragma unroll
    for (int j = 0; j < 4; j++) o[i][j] = 0.f;

  const float* wtp = WT + 4 * tx;
  float4 t0 = *(const float4*)(wtp);
  for (int k = 0; k < K_DIM; k++) {
    float4 nt;
    if (k < K_DIM - 1) nt = *(const float4*)(wtp + (k + 1) * D_DIM);
    float p0 = buf[k * 65 + 4 * ty + 0];
    float p1 = buf[k * 65 + 4 * ty + 1];
    float p2 = buf[k * 65 + 4 * ty + 2];
    float p3 = buf[k * 65 + 4 * ty + 3];
    float pv[4] = {p0, p1, p2, p3};
    float tv[4] = {t0.x, t0.y, t0.z, t0.w};
#pragma unroll
    for (int i = 0; i < 4; i++)
#pragma unroll
      for (int j = 0; j < 4; j++) o[i][j] = fmaf(pv[i], tv[j], o[i][j]);
    t0 = nt;
  }

  // Epilogue: fold inv_s, row inv-norms (tx-group reduce), coalesced stores.
  float ns[4];
#pragma unroll
  for (int i = 0; i < 4; i++) {
    float s = 0.f;
#pragma unroll
    for (int j = 0; j < 4; j++) {
      o[i][j] *= inv_s[i];
      s = fmaf(o[i][j], o[i][j], s);
    }
    ns[i] = s;
  }
#pragma unroll
  for (int off = 1; off <= 8; off <<= 1)
#pragma unroll
    for (int i = 0; i < 4; i++) ns[i] += __shfl_xor(ns[i], off, 64);
  if (tx == 0) {
#pragma unroll
    for (int i = 0; i < 4; i++) {
      int r = 4 * ty + i;
      if (r < cnt) invn_i[n0 + r] = 1.f / fmaxf(sqrtf(ns[i]), EPSF);
    }
  }
#pragma unroll
  for (int i = 0; i < 4; i++) {
    int r = 4 * ty + i;
    if (r < cnt) {
      float4 v = make_float4(o[i][0], o[i][1], o[i][2], o[i][3]);
      *(float4*)(intl + (size_t)(n0 + r) * D_DIM + 4 * tx) = v;
    }
  }
}

// Fused adaptive pass: 4 edges/iter, float4 lanes. Computes both alphas, row
// sums, alpha-weighted ek accum (d_inv factored out), gaa/iaa, and either
// ek_next (LAST=false) or fin = ek0 + ek1 + ek2 (LAST=true).
template <bool LAST>
__global__ void passB_kernel(const float* __restrict__ ek, const float* __restrict__ gnn,
                             const float* __restrict__ intl, const float* __restrict__ invn_g,
                             const float* __restrict__ invn_i, const int* __restrict__ t_sorted,
                             const int* __restrict__ row_ptr, float* __restrict__ gaa,
                             float* __restrict__ iaa, float* __restrict__ ek_next,
                             const float* __restrict__ ek0, float* __restrict__ fin) {
  int wv = threadIdx.x >> 6, lane = threadIdx.x & 63;
  int slot = lane >> 4, f = (lane & 15) << 2;
  int n = blockIdx.x * 4 + wv;
  if (n >= N_CNT) return;
  int start = row_ptr[n], end = row_ptr[n + 1];
  const float4 gh = *(const float4*)(gnn + (size_t)n * D_DIM + f);
  const float4 ih = *(const float4*)(intl + (size_t)n * D_DIM + f);
  float ig = invn_g[n], ii = invn_i[n];
  float rs_g = 0.f, rs_i = 0.f;
  float gx = 0.f, gy = 0.f, gz = 0.f, gw = 0.f;
  float ix = 0.f, iy = 0.f, iz = 0.f, iw = 0.f;
  for (int i = start; i < end; i += 4) {
    int idx = i + slot;
    int ic = (idx < end) ? idx : (end - 1);
    int t = t_sorted[ic];
    size_t rb = (size_t)t * D_DIM + f;
    const float4 gt = *(const float4*)(gnn + rb);
    const float4 it = *(const float4*)(intl + rb);
    const float4 et = *(const float4*)(ek + rb);
    float ivg = invn_g[t];
    float ivi = invn_i[t];
    float dg = gh.x * gt.x + gh.y * gt.y + gh.z * gt.z + gh.w * gt.w;
    float di = ih.x * it.x + ih.y * it.y + ih.z * it.z + ih.w * it.w;
#pragma unroll
    for (int off = 1; off <= 8; off <<= 1) {
      dg += __shfl_xor(dg, off, 64);
      di += __shfl_xor(di, off, 64);
    }
    float ag = fmaf(dg * ig, ivg, 1.f) * 0.5f;
    float ai = fmaf(di * ii, ivi, 1.f) * 0.5f;
    if (idx >= end) { ag = 0.f; ai = 0.f; }
    rs_g += ag;
    rs_i += ai;
    gx = fmaf(ag, et.x, gx);
    gy = fmaf(ag, et.y, gy);
    gz = fmaf(ag, et.z, gz);
    gw = fmaf(ag, et.w, gw);
    ix = fmaf(ai, et.x, ix);
    iy = fmaf(ai, et.y, iy);
    iz = fmaf(ai, et.z, iz);
    iw = fmaf(ai, et.w, iw);
  }
#pragma unroll
  for (int off = 16; off <= 32; off <<= 1) {
    rs_g += __shfl_xor(rs_g, off, 64);
    rs_i += __shfl_xor(rs_i, off, 64);
    gx += __shfl_xor(gx, off, 64);
    gy += __shfl_xor(gy, off, 64);
    gz += __shfl_xor(gz, off, 64);
    gw += __shfl_xor(gw, off, 64);
    ix += __shfl_xor(ix, off, 64);
    iy += __shfl_xor(iy, off, 64);
    iz += __shfl_xor(iz, off, 64);
    iw += __shfl_xor(iw, off, 64);
  }
  float dgi = (rs_g > 0.f) ? 1.f / rs_g : 0.f;
  float dii = (rs_i > 0.f) ? 1.f / rs_i : 0.f;
  if (slot == 0) {
    size_t ob = (size_t)n * D_DIM + f;
    float4 ga = make_float4(gx * dgi, gy * dgi, gz * dgi, gw * dgi);
    float4 ia = make_float4(ix * dii, iy * dii, iz * dii, iw * dii);
    nt_store4(gaa + ob, ga);
    nt_store4(iaa + ob, ia);
    const float4 eh = *(const float4*)(ek + ob);
    float4 en = make_float4(gh.x + ih.x + ga.x + ia.x + eh.x, gh.y + ih.y + ga.y + ia.y + eh.y,
                            gh.z + ih.z + ga.z + ia.z + eh.z, gh.w + ih.w + ga.w + ia.w + eh.w);
    if (LAST) {
      // fin = ek0 + ek1 + ek2 = ek0 + eh + en
      const float4 e0 = *(const float4*)(ek0 + ob);
      float4 fo = make_float4(e0.x + eh.x + en.x, e0.y + eh.y + en.y, e0.z + eh.z + en.z,
                              e0.w + eh.w + en.w);
      nt_store4(fin + ob, fo);
    } else {
      *(float4*)(ek_next + ob) = en;
    }
  }
}

extern "C" void kernel_launch(void* const* d_in, const int* in_sizes, int n_in, void* d_out,
                              int out_size, void* d_ws, size_t ws_size, hipStream_t stream) {
  const float* user_emb = (const float*)d_in[0];
  const float* item_emb = (const float*)d_in[1];
  const float* user_intent = (const float*)d_in[2];
  const float* item_intent = (const float*)d_in[3];
  const float* adj_vals = (const float*)d_in[4];
  const int* h_idx = (const int*)d_in[5];
  const int* t_idx = (const int*)d_in[6];

  float* out = (float*)d_out;
  float* fin = out;
  float* gnn_base = out + (size_t)N_CNT * D_DIM;
  float* intl_base = gnn_base + (size_t)L_LAYERS * N_CNT * D_DIM;
  float* gaa_base = intl_base + (size_t)L_LAYERS * N_CNT * D_DIM;
  float* iaa_base = gaa_base + (size_t)L_LAYERS * N_CNT * D_DIM;

  float* ws = (float*)d_ws;
  float* ekA = ws;                                // N*D (ek0 — preserved)
  float* ekB = ekA + (size_t)N_CNT * D_DIM;       // N*D (ek1)
  float* ekC = ekB + (size_t)N_CNT * D_DIM;       // N*D (spare / ek2 if L>2)
  float* v_sorted = ekC + (size_t)N_CNT * D_DIM;  // E
  float* invn_g = v_sorted + E_CNT;               // N
  float* invn_i = invn_g + N_CNT;                 // N
  int* t_sorted = (int*)(invn_i + N_CNT);         // E
  int* row_ptr = t_sorted + E_CNT;                // N+1
  int* counts = row_ptr + (N_CNT + 1);            // N
  int* cursor = counts + N_CNT;                   // N
  int* partial = cursor + N_CNT;                  // SC_BLOCKS
  int* offs = partial + SC_BLOCKS;                // SC_BLOCKS
  float* wtu = (float*)(offs + SC_BLOCKS);        // D*K  (W_u^T)
  float* wti = wtu + (size_t)D_DIM * K_DIM;       // D*K  (W_i^T)

  (void)hipMemsetAsync(counts, 0, N_CNT * sizeof(int), stream);
  init_kernel<<<2048, 256, 0, stream>>>(user_emb, item_emb, ekA);
  hist_kernel<<<2048, 256, 0, stream>>>(h_idx, counts);
  transposeW_kernel<<<32, 512, 0, stream>>>(user_intent, item_intent, wtu, wti);
  scanA_kernel<<<SC_BLOCKS, SC_TPB, 0, stream>>>(counts, partial);
  scanB_kernel<<<1, SC_BLOCKS, 0, stream>>>(partial, offs);
  scanC_kernel<<<SC_BLOCKS, SC_TPB, 0, stream>>>(counts, offs, row_ptr, cursor);
  scatter_kernel<<<2048, 256, 0, stream>>>(h_idx, t_idx, adj_vals, cursor, t_sorted, v_sorted);

  const int nodeBlocks = (N_CNT + 3) / 4;
  const int intentBlocks = UBLK + IBLK;

  // Layer 0: ekA (ek0) -> ekB (ek1). Layer 1 (last): fin = ekA + ekB + en.
  float* ek = ekA;
  float* ekn = ekB;
  for (int l = 0; l < L_LAYERS; l++) {
    float* gnn = gnn_base + (size_t)l * N_CNT * D_DIM;
    float* intl = intl_base + (size_t)l * N_CNT * D_DIM;
    float* gaa = gaa_base + (size_t)l * N_CNT * D_DIM;
    float* iaa = iaa_base + (size_t)l * N_CNT * D_DIM;
    spmm_gnn_kernel<<<nodeBlocks, 256, 0, stream>>>(ek, t_sorted, v_sorted, row_ptr, gnn, invn_g);
    intent_kernel<<<intentBlocks, 256, 0, stream>>>(ek, user_intent, wtu, item_intent, wti, intl,
                                                    invn_i);
    if (l == L_LAYERS - 1) {
      passB_kernel<true><<<nodeBlocks, 256, 0, stream>>>(ek, gnn, intl, invn_g, invn_i, t_sorted,
                                                         row_ptr, gaa, iaa, nullptr, ekA, fin);
    } else {
      passB_kernel<false><<<nodeBlocks, 256, 0, stream>>>(ek, gnn, intl, invn_g, invn_i, t_sorted,
                                                          row_ptr, gaa, iaa, ekn, nullptr, nullptr);
      float* tmp = ek;
      ek = ekn;
      ekn = (l == 0) ? ekC : tmp;  // never clobber ekA (ek0, needed by last layer)
    }
  }
}